// Round 10
// baseline (458.133 us; speedup 1.0000x reference)
//
#include <hip/hip_runtime.h>
#include <math.h>

#define BATCH 4
#define CIN   512
#define PABN  64
#define HW    4096
#define PROW  4356            // 66*66 padded pixel rows

typedef __attribute__((ext_vector_type(8))) short bfrag;   // 8 bf16
typedef __attribute__((ext_vector_type(4))) float ffrag;   // 4 fp32
#define MFMA(a, b, c) __builtin_amdgcn_mfma_f32_16x16x32_bf16(a, b, c, 0, 0, 0)

__device__ __forceinline__ void gload16(const void* g, void* l) {
    __builtin_amdgcn_global_load_lds(
        (const __attribute__((address_space(1))) unsigned int*)g,
        (__attribute__((address_space(3))) unsigned int*)l, 16, 0, 0);
}

__device__ __forceinline__ unsigned f2bf(float f) {   // fp32 -> bf16 bits, RNE
    unsigned u = __float_as_uint(f);
    return (u + 0x7fffu + ((u >> 16) & 1u)) >> 16;
}

// padded row index for pixel n: (h+1)*66 + (w+1) = n + 2*(n>>6) + 67
__device__ __forceinline__ int prow(int n) { return n + 2 * (n >> 6) + 67; }

// ---------------------------------------------------------------------------
__global__ __launch_bounds__(256) void k_fill0(uint4* __restrict__ p) {
    uint4 z; z.x = z.y = z.z = z.w = 0u;
    p[(size_t)blockIdx.x * 256 + threadIdx.x] = z;
}

// w_top/w_cen [64][512] fp32 -> bf16 (layout kept: [p][i], K=i contiguous)
__global__ __launch_bounds__(256) void k_wpc(const float* __restrict__ wt,
        const float* __restrict__ wc, short* __restrict__ ot, short* __restrict__ oc) {
    const float* src = blockIdx.y ? wc : wt;
    short* dst       = blockIdx.y ? oc : ot;
    int idx = (blockIdx.x * 256 + threadIdx.x) * 4;
    float4 v = *(const float4*)(src + idx);
    uint2 u;
    u.x = f2bf(v.x) | (f2bf(v.y) << 16);
    u.y = f2bf(v.z) | (f2bf(v.w) << 16);
    *(uint2*)(dst + idx) = u;
}

// w [O][I][3][3] fp32 -> wT[k][o][i] bf16
__global__ __launch_bounds__(256) void k_w9(const float* __restrict__ wb,
        const float* __restrict__ wo, short* __restrict__ wbT, short* __restrict__ woT) {
    const float* w = blockIdx.z ? wo : wb;
    short* wT      = blockIdx.z ? woT : wbT;
    int o = blockIdx.x;
    int i = blockIdx.y * 256 + threadIdx.x;
    const float* src = w + ((size_t)o * CIN + i) * 9;
    float v[9];
#pragma unroll
    for (int k = 0; k < 9; k++) v[k] = src[k];
#pragma unroll
    for (int k = 0; k < 9; k++)
        wT[((size_t)k * CIN + o) * CIN + i] = (short)f2bf(v[k]);
}

// ---------------------------------------------------------------------------
// x [B][512][4096] fp32 (ADD: + invZ * O [n][c] fp32, raw-reshape-equivalent) ->
// pixel-major padded bf16 xp [B][4356][512]. Borders pre-zeroed by k_fill0.
// grid (64 pix-tiles, 8 ch-tiles, B)
template <bool ADD>
__global__ __launch_bounds__(256) void k_padT(const float* __restrict__ x,
        const float* __restrict__ Oc, const float* __restrict__ Zp,
        short* __restrict__ xp) {
    __shared__ float Ts[64][68];
    int t = threadIdx.x;
    int n0 = blockIdx.x * 64, c0 = blockIdx.y * 64, b = blockIdx.z;
    float iz = ADD ? (1.0f / Zp[b]) : 1.0f;
    const float* xb = x + ((size_t)b * CIN + c0) * HW;
#pragma unroll
    for (int j = 0; j < 4; j++) {
        int slot = j * 256 + t;
        int r = slot >> 4, col = (slot & 15) * 4;
        float4 v = *(const float4*)(xb + (size_t)r * HW + n0 + col);
        *(float4*)&Ts[r][col] = v;
    }
    __syncthreads();
    short* xpb = xp + (size_t)b * PROW * CIN;
    const float* ob = ADD ? (Oc + (size_t)b * HW * CIN) : nullptr;
#pragma unroll
    for (int j = 0; j < 2; j++) {
        int slot = j * 256 + t;
        int pix = slot >> 3, ch = (slot & 7) * 8;
        int rp = prow(n0 + pix);
        float v[8];
#pragma unroll
        for (int k = 0; k < 8; k++) v[k] = Ts[ch + k][pix];
        if (ADD) {
            const float* os = ob + (size_t)(n0 + pix) * CIN + c0 + ch;
#pragma unroll
            for (int k = 0; k < 8; k += 4) {
                float4 o4 = *(const float4*)(os + k);
                v[k]   += o4.x * iz; v[k+1] += o4.y * iz;
                v[k+2] += o4.z * iz; v[k+3] += o4.w * iz;
            }
        }
        unsigned pk[4];
#pragma unroll
        for (int k = 0; k < 4; k++)
            pk[k] = f2bf(v[2*k]) | (f2bf(v[2*k+1]) << 16);
        *(uint4*)(xpb + (size_t)rp * CIN + c0 + ch) = *(uint4*)pk;
    }
}

// ---------------------------------------------------------------------------
// 1x1 convs: xt/xc[n][p] = sum_i xp[n][i]*w[p][i] + bias.  M=p(64), N=n(64), K=512
// grid (64 n-tiles, 8: b*2+which)
__global__ __launch_bounds__(256) void k_qk(const short* __restrict__ xp,
        const short* __restrict__ wtop, const short* __restrict__ wcen,
        const float* __restrict__ btop, const float* __restrict__ bcen,
        short* __restrict__ xt, short* __restrict__ xc) {
    __shared__ __align__(16) short As[2048];   // w: 64 rows(p) x 32(i)
    __shared__ __align__(16) short Bs[2048];   // x: 64 rows(n) x 32(i)
    int t = threadIdx.x;
    int n0 = blockIdx.x * 64;
    int b = blockIdx.y >> 1, which = blockIdx.y & 1;
    const short* w    = which ? wcen : wtop;
    const float* bias = which ? bcen : btop;
    short* out        = (which ? xc : xt) + (size_t)b * HW * PABN;
    const short* xb   = xp + (size_t)b * PROW * CIN;

    int arow = t >> 2, ach = t & 3;
    int sch = ach ^ ((arow >> 1) & 3);
    int rp = prow(n0 + arow);
    int lane = t & 63, wid = t >> 6, l15 = lane & 15, q = lane >> 4;
    int wm = wid >> 1, wn = wid & 1;
    int cx = (q ^ ((l15 >> 1) & 3)) * 8;
    ffrag acc[2][2] = {};

    for (int i0 = 0; i0 < CIN; i0 += 32) {
        gload16(w  + (size_t)arow * CIN + i0 + sch * 8, As + t * 8);
        gload16(xb + (size_t)rp   * CIN + i0 + sch * 8, Bs + t * 8);
        __syncthreads();
        bfrag a[2], bb[2];
        a[0]  = *(const bfrag*)(As + (wm * 32 + l15) * 32 + cx);
        a[1]  = *(const bfrag*)(As + (wm * 32 + 16 + l15) * 32 + cx);
        bb[0] = *(const bfrag*)(Bs + (wn * 32 + l15) * 32 + cx);
        bb[1] = *(const bfrag*)(Bs + (wn * 32 + 16 + l15) * 32 + cx);
        acc[0][0] = MFMA(a[0], bb[0], acc[0][0]);
        acc[0][1] = MFMA(a[0], bb[1], acc[0][1]);
        acc[1][0] = MFMA(a[1], bb[0], acc[1][0]);
        acc[1][1] = MFMA(a[1], bb[1], acc[1][1]);
        __syncthreads();
    }
#pragma unroll
    for (int mi = 0; mi < 2; mi++) {
        int p = wm * 32 + mi * 16 + q * 4;
        float4 bv = *(const float4*)(bias + p);
#pragma unroll
        for (int ni = 0; ni < 2; ni++) {
            int nn = n0 + wn * 32 + ni * 16 + l15;
            ffrag v = acc[mi][ni];
            uint2 u;
            u.x = f2bf(v.x + bv.x) | (f2bf(v.y + bv.y) << 16);
            u.y = f2bf(v.z + bv.z) | (f2bf(v.w + bv.w) << 16);
            *(uint2*)(out + (size_t)nn * PABN + p) = u;
        }
    }
}

// ---------------------------------------------------------------------------
// conv3x3 v3 (kept — round-8 win): counted-vmcnt pipeline, vmcnt(8) with
// full-iteration slack, per-tap hoisted addressing. LDS 64KB dbuf.
// M=n(128), N=o(128). grid (32 n-tiles, 4 o-tiles, B)
template <bool FP32OUT>
__global__ __launch_bounds__(256) void k_conv(const short* __restrict__ xin,
        const short* __restrict__ wT, const float* __restrict__ bias,
        void* __restrict__ outv) {
    __shared__ __align__(16) short As[2][8192];   // pixels: 128 x 64
    __shared__ __align__(16) short Bs[2][8192];   // weights: 128(o) x 64
    int t = threadIdx.x;
    int n0 = blockIdx.x * 128, o0 = blockIdx.y * 128, b = blockIdx.z;
    const short* xb = xin + (size_t)b * PROW * CIN;
    int lane = t & 63, wid = t >> 6, l15 = lane & 15, q = lane >> 4;
    int wm = wid >> 1, wn = wid & 1;
    int arow = t >> 3, ach = t & 7;
    int sch = ach ^ (arow & 7);
    int pr[4];
#pragma unroll
    for (int j = 0; j < 4; j++) pr[j] = prow(n0 + j * 32 + arow);
    ffrag acc[4][4] = {};

    auto stage = [&](int k9s, int i0, int bsel) {
        int kh = k9s / 3, kw = k9s - kh * 3;       // hoisted per-tap by unroll
        int sh = (kh - 1) * 66 + (kw - 1);
        const short* wk = wT + (size_t)k9s * CIN * CIN;
#pragma unroll
        for (int j = 0; j < 4; j++) {
            gload16(xb + (size_t)(pr[j] + sh) * CIN + i0 + sch * 8,
                    &As[bsel][(j * 256 + t) * 8]);
            gload16(wk + (size_t)(o0 + j * 32 + arow) * CIN + i0 + sch * 8,
                    &Bs[bsel][(j * 256 + t) * 8]);
        }
    };

    stage(0, 0, 0);                                // pipeline prologue

    for (int k9 = 0; k9 < 9; ++k9) {
#pragma unroll
        for (int i8 = 0; i8 < 8; ++i8) {
            int ks = k9 * 8 + i8;
            int cur = i8 & 1;                      // == ks & 1
            if (ks < 71) {                         // issue next-step loads
                if (i8 < 7) stage(k9, (i8 + 1) * 64, cur ^ 1);
                else        stage(k9 + 1, 0, cur ^ 1);
                asm volatile("s_waitcnt vmcnt(8)" ::: "memory");  // stage(ks) in
            } else {
                asm volatile("s_waitcnt vmcnt(0)" ::: "memory");
            }
            __builtin_amdgcn_s_barrier();          // B1: tile ks visible to all
            asm volatile("" ::: "memory");
            __builtin_amdgcn_s_setprio(1);
#pragma unroll
            for (int kc = 0; kc < 2; kc++) {
                int cx = (((kc * 4 + q) ^ (l15 & 7))) * 8;
                bfrag a[4], bb[4];
#pragma unroll
                for (int mi = 0; mi < 4; mi++)
                    a[mi] = *(const bfrag*)(&As[cur][(wm * 64 + mi * 16 + l15) * 64 + cx]);
#pragma unroll
                for (int ni = 0; ni < 4; ni++)
                    bb[ni] = *(const bfrag*)(&Bs[cur][(wn * 64 + ni * 16 + l15) * 64 + cx]);
#pragma unroll
                for (int mi = 0; mi < 4; mi++)
#pragma unroll
                    for (int ni = 0; ni < 4; ni++)
                        acc[mi][ni] = MFMA(a[mi], bb[ni], acc[mi][ni]);
            }
            __builtin_amdgcn_s_setprio(0);
            asm volatile("" ::: "memory");
            __builtin_amdgcn_s_barrier();          // B2: reads of buf cur done
            asm volatile("" ::: "memory");
        }
    }
#pragma unroll
    for (int ni = 0; ni < 4; ni++) {
        int o = o0 + wn * 64 + ni * 16 + l15;
        float bv = bias[o];
#pragma unroll
        for (int mi = 0; mi < 4; mi++) {
            int n = n0 + wm * 64 + mi * 16 + q * 4;
            ffrag v = acc[mi][ni];
            if (FP32OUT) {
                float* out = (float*)outv + (size_t)b * CIN * HW;
                *(float4*)(out + (size_t)o * HW + n) =
                    make_float4(v.x + bv, v.y + bv, v.z + bv, v.w + bv);
            } else {
                short* out = (short*)outv + (size_t)b * CIN * HW;
                uint2 u;
                u.x = f2bf(v.x + bv) | (f2bf(v.y + bv) << 16);
                u.y = f2bf(v.z + bv) | (f2bf(v.w + bv) << 16);
                *(uint2*)(out + (size_t)o * HW + n) = u;
            }
        }
    }
}

// ---------------------------------------------------------------------------
// Fused S+PV v7: multi-block TLP — 4-wave blocks, tile 64n x 128c (c-quarter),
// LDS exactly 40960 B -> up to 4 blocks/CU resident (16 waves, 2x occupancy
// of v1/v5). Theory: v1/v3/v5 all ~4600 cyc/iter because one lockstep block
// per CU exposes every vmcnt/barrier stall; independent co-resident blocks
// hide them (conv v3 evidence). S/exp duplicated per c-quarter (proven cheap:
// v1 dup ~= v5 single). Per iter, v5 skeleton:
//   A: issue XT(it+1) x2; S 8 MFMA; exp 16 -> PS
//   B1: vmcnt(2) [retires XB(it) 4-group; XT(it+1) stays in flight] + lgkm(0)
//   PV 16 MFMA (XB + PS); vmcnt(0) [XT(it+1) in]; B2
//   C: issue XB(it+1) x4 (lands under next A+S, full-phase slack)
// grid 1024 = 4b x 4cq x 64n, XCD-chunked.
__global__ __launch_bounds__(256) void k_fused(const short* __restrict__ xc,
        const short* __restrict__ xt, const short* __restrict__ xb,
        float* __restrict__ O, float* __restrict__ Zbuf) {
    __shared__ __align__(16) short SM[20480];   // 40960 B exactly
    short* XT0 = SM;                  // [2][64][64]
    short* XBs = SM + 8192;           // [128][64]
    short* PS  = SM + 16384;          // [64][64]  (reused as red at end)

    int bid = blockIdx.x;
    int wg = ((bid & 7) << 7) | (bid >> 3);     // XCD-chunked (1024%8==0)
    int b = wg >> 8, cq = (wg >> 6) & 3, ntile = wg & 63;
    int n0 = ntile * 64, c0 = cq * 128;
    const short* xcb = xc + (size_t)b * HW * PABN;
    const short* xtb = xt + (size_t)b * HW * PABN;
    const short* xbb = xb + (size_t)b * CIN * HW + (size_t)c0 * HW;

    int t = threadIdx.x;
    int lane = t & 63, wid = t >> 6, l15 = lane & 15, q = lane >> 4;
    int srow = t >> 3, sch = (t & 7) ^ (srow & 7);   // staging row / swz chunk

    // ---- prologue: XC -> PS area, XT(0), XB(0)
    gload16(xcb + (size_t)(n0 + srow) * PABN + sch * 8, PS + t * 8);
    gload16(xcb + (size_t)(n0 + srow + 32) * PABN + sch * 8, PS + (256 + t) * 8);
    gload16(xtb + (size_t)srow * PABN + sch * 8, XT0 + t * 8);
    gload16(xtb + (size_t)(srow + 32) * PABN + sch * 8, XT0 + (256 + t) * 8);
#pragma unroll
    for (int j = 0; j < 4; j++)
        gload16(xbb + (size_t)(j * 32 + srow) * HW + sch * 8,
                XBs + (j * 256 + t) * 8);
    asm volatile("s_waitcnt vmcnt(0)" ::: "memory");
    __builtin_amdgcn_s_barrier();
    asm volatile("" ::: "memory");
    bfrag aS[2];                                // loop-invariant xc A-frags
#pragma unroll
    for (int kc = 0; kc < 2; kc++)
        aS[kc] = *(const bfrag*)(PS + (wid * 16 + l15) * 64
                                 + ((kc * 4 + q) ^ (l15 & 7)) * 8);
    asm volatile("s_waitcnt lgkmcnt(0)" ::: "memory");
    __builtin_amdgcn_s_barrier();               // PS now reusable
    asm volatile("" ::: "memory");

    ffrag acc[2][4] = {};
    float zacc = 0.f;
    int nrow = wid * 16 + q * 4;

    for (int it = 0; it < 64; ++it) {
        const short* XTc = XT0 + (it & 1) * 4096;
        // ---- A: issue XT(it+1); S(it): wave owns n-rows [wid*16,+16) x m64
        if (it < 63) {
            short* XTn = XT0 + ((it & 1) ^ 1) * 4096;
            const short* src = xtb + (size_t)((it + 1) * 64 + srow) * PABN + sch * 8;
            gload16(src, XTn + t * 8);
            gload16(src + 32 * PABN, XTn + (256 + t) * 8);
        }
        ffrag s[4] = {};
        __builtin_amdgcn_s_setprio(1);
#pragma unroll
        for (int ni = 0; ni < 4; ni++)
#pragma unroll
            for (int kc = 0; kc < 2; kc++) {
                bfrag bf = *(const bfrag*)(XTc + (ni * 16 + l15) * 64
                                           + ((kc * 4 + q) ^ (l15 & 7)) * 8);
                s[ni] = MFMA(aS[kc], bf, s[ni]);
            }
        __builtin_amdgcn_s_setprio(0);
        // exp + PS write (chunk-swizzled)
#pragma unroll
        for (int ni = 0; ni < 4; ni++) {
            int cc = ni * 2 + (l15 >> 3), jj = l15 & 7;
#pragma unroll
            for (int r = 0; r < 4; r++) {
                float e = __expf(s[ni][r]);
                zacc += e;
                PS[(nrow + r) * 64 + (cc ^ ((nrow + r) & 7)) * 8 + jj] =
                    (short)f2bf(e);
            }
        }
        if (it < 63) asm volatile("s_waitcnt vmcnt(2) lgkmcnt(0)" ::: "memory");
        else         asm volatile("s_waitcnt vmcnt(0) lgkmcnt(0)" ::: "memory");
        __builtin_amdgcn_s_barrier();           // B1: PS(it)+XB(it) visible
        asm volatile("" ::: "memory");
        // ---- PV: acc[c][n] += xb . P^T  (wave: c-32 x n-64)
        __builtin_amdgcn_s_setprio(1);
#pragma unroll
        for (int kc = 0; kc < 2; kc++) {
            int cx = ((kc * 4 + q) ^ (l15 & 7)) * 8;
            bfrag av[2], bv[4];
#pragma unroll
            for (int ci = 0; ci < 2; ci++)
                av[ci] = *(const bfrag*)(XBs + (wid * 32 + ci * 16 + l15) * 64 + cx);
#pragma unroll
            for (int nj = 0; nj < 4; nj++)
                bv[nj] = *(const bfrag*)(PS + (nj * 16 + l15) * 64 + cx);
#pragma unroll
            for (int ci = 0; ci < 2; ci++)
#pragma unroll
                for (int nj = 0; nj < 4; nj++)
                    acc[ci][nj] = MFMA(av[ci], bv[nj], acc[ci][nj]);
        }
        __builtin_amdgcn_s_setprio(0);
        if (it < 63) asm volatile("s_waitcnt vmcnt(0)" ::: "memory"); // XT(it+1)
        __builtin_amdgcn_s_barrier();           // B2: XB/PS reads done
        asm volatile("" ::: "memory");
        // ---- C: issue XB(it+1) (lands under next A phase; checked at next B1)
        if (it < 63) {
            int m1 = (it + 1) * 64;
#pragma unroll
            for (int j = 0; j < 4; j++)
                gload16(xbb + (size_t)(j * 32 + srow) * HW + m1 + sch * 8,
                        XBs + (j * 256 + t) * 8);
        }
    }

    // ---- z reduce (cq==0 blocks only; all quarters computed identical S)
#pragma unroll
    for (int off = 32; off > 0; off >>= 1) zacc += __shfl_down(zacc, off, 64);
    __syncthreads();                            // last PV PS-reads done
    float* red = (float*)PS;                    // PS dead; reuse
    if (lane == 0) red[wid] = zacc;
    __syncthreads();
    if (cq == 0 && t == 0)
        Zbuf[b * 64 + ntile] = red[0] + red[1] + red[2] + red[3];
    // ---- O store (unscaled fp32, [n][c]; invZ applied in k_padT<true>)
    float* Ob = O + (size_t)b * HW * CIN;
#pragma unroll
    for (int ci = 0; ci < 2; ci++)
#pragma unroll
        for (int nj = 0; nj < 4; nj++) {
            int n = n0 + nj * 16 + l15;
            int c = c0 + wid * 32 + ci * 16 + q * 4;
            ffrag v = acc[ci][nj];
            *(float4*)(Ob + (size_t)n * CIN + c) =
                make_float4(v.x, v.y, v.z, v.w);
        }
}

// ---------------------------------------------------------------------------
// Reduce Zbuf[b][0..63] -> Z[b]. 1 block, 256 thr (wave per batch).
__global__ __launch_bounds__(256) void k_redz(const float* __restrict__ Zbuf,
        float* __restrict__ Z) {
    int wid = threadIdx.x >> 6, lane = threadIdx.x & 63;
    float s = Zbuf[wid * 64 + lane];
#pragma unroll
    for (int off = 32; off > 0; off >>= 1) s += __shfl_down(s, off, 64);
    if (lane == 0) Z[wid] = s;
}

// ---------------------------------------------------------------------------
extern "C" void kernel_launch(void* const* d_in, const int* in_sizes, int n_in,
                              void* d_out, int out_size, void* d_ws, size_t ws_size,
                              hipStream_t stream) {
    const float* x     = (const float*)d_in[0];
    const float* w_top = (const float*)d_in[1];
    const float* b_top = (const float*)d_in[2];
    const float* w_cen = (const float*)d_in[3];
    const float* b_cen = (const float*)d_in[4];
    const float* w_bot = (const float*)d_in[5];
    const float* b_bot = (const float*)d_in[6];
    const float* w_out = (const float*)d_in[7];
    const float* b_out = (const float*)d_in[8];

    char* W = (char*)d_ws;
    short* xp   = (short*)(W);               // 17,842,176 B (also reused as yp)
    short* xt   = (short*)(W + 17842176);    //  2,097,152
    short* xc   = (short*)(W + 19939328);    //  2,097,152
    short* wtb  = (short*)(W + 22036480);    //     65,536
    short* wcb  = (short*)(W + 22102016);    //     65,536
    short* wbT  = (short*)(W + 22167552);    //  4,718,592
    short* woT  = (short*)(W + 26886144);    //  4,718,592
    short* xbc  = (short*)(W + 31604736);    // 16,777,216
    float* O    = (float*)(W + 48381952);    // 33,554,432 (unscaled PV output)
    float* Z    = (float*)(W + 81936384);    //        512
    float* Zbuf = (float*)(W + 81936896);    //     16,384 (uses 256 floats)

    k_fill0<<<4356, 256, 0, stream>>>((uint4*)xp);           // zero padded buffer
    k_wpc<<<dim3(32, 2), 256, 0, stream>>>(w_top, w_cen, wtb, wcb);
    k_w9<<<dim3(512, 2, 2), 256, 0, stream>>>(w_bot, w_out, wbT, woT);
    k_padT<false><<<dim3(64, 8, BATCH), 256, 0, stream>>>(x, nullptr, nullptr, xp);
    k_qk<<<dim3(64, 8), 256, 0, stream>>>(xp, wtb, wcb, b_top, b_cen, xt, xc);
    k_conv<false><<<dim3(32, 4, BATCH), 256, 0, stream>>>(xp, wbT, b_bot, xbc);
    k_fused<<<dim3(1024), 256, 0, stream>>>(xc, xt, xbc, O, Zbuf);
    k_redz<<<1, 256, 0, stream>>>(Zbuf, Z);
    k_padT<true><<<dim3(64, 8, BATCH), 256, 0, stream>>>(x, O, Z, xp);  // y -> xp
    k_conv<true><<<dim3(32, 4, BATCH), 256, 0, stream>>>(xp, woT, b_out, (float*)d_out);
}

// Round 11
// 392.548 us; speedup vs baseline: 1.1671x; 1.1671x over previous
//
#include <hip/hip_runtime.h>
#include <math.h>

#define BATCH 4
#define CIN   512
#define PABN  64
#define HW    4096
#define PROW  4356            // 66*66 padded pixel rows

typedef __attribute__((ext_vector_type(8))) short bfrag;   // 8 bf16
typedef __attribute__((ext_vector_type(4))) float ffrag;   // 4 fp32
#define MFMA(a, b, c) __builtin_amdgcn_mfma_f32_16x16x32_bf16(a, b, c, 0, 0, 0)

__device__ __forceinline__ void gload16(const void* g, void* l) {
    __builtin_amdgcn_global_load_lds(
        (const __attribute__((address_space(1))) unsigned int*)g,
        (__attribute__((address_space(3))) unsigned int*)l, 16, 0, 0);
}

__device__ __forceinline__ unsigned f2bf(float f) {   // fp32 -> bf16 bits, RNE
    unsigned u = __float_as_uint(f);
    return (u + 0x7fffu + ((u >> 16) & 1u)) >> 16;
}

// padded row index for pixel n: (h+1)*66 + (w+1) = n + 2*(n>>6) + 67
__device__ __forceinline__ int prow(int n) { return n + 2 * (n >> 6) + 67; }

// ---------------------------------------------------------------------------
__global__ __launch_bounds__(256) void k_fill0(uint4* __restrict__ p) {
    uint4 z; z.x = z.y = z.z = z.w = 0u;
    p[(size_t)blockIdx.x * 256 + threadIdx.x] = z;
}

// w_top/w_cen [64][512] fp32 -> bf16 (layout kept: [p][i], K=i contiguous)
__global__ __launch_bounds__(256) void k_wpc(const float* __restrict__ wt,
        const float* __restrict__ wc, short* __restrict__ ot, short* __restrict__ oc) {
    const float* src = blockIdx.y ? wc : wt;
    short* dst       = blockIdx.y ? oc : ot;
    int idx = (blockIdx.x * 256 + threadIdx.x) * 4;
    float4 v = *(const float4*)(src + idx);
    uint2 u;
    u.x = f2bf(v.x) | (f2bf(v.y) << 16);
    u.y = f2bf(v.z) | (f2bf(v.w) << 16);
    *(uint2*)(dst + idx) = u;
}

// w [O][I][3][3] fp32 -> wT[k][o][i] bf16
__global__ __launch_bounds__(256) void k_w9(const float* __restrict__ wb,
        const float* __restrict__ wo, short* __restrict__ wbT, short* __restrict__ woT) {
    const float* w = blockIdx.z ? wo : wb;
    short* wT      = blockIdx.z ? woT : wbT;
    int o = blockIdx.x;
    int i = blockIdx.y * 256 + threadIdx.x;
    const float* src = w + ((size_t)o * CIN + i) * 9;
    float v[9];
#pragma unroll
    for (int k = 0; k < 9; k++) v[k] = src[k];
#pragma unroll
    for (int k = 0; k < 9; k++)
        wT[((size_t)k * CIN + o) * CIN + i] = (short)f2bf(v[k]);
}

// ---------------------------------------------------------------------------
// x [B][512][4096] fp32 (ADD: + invZ * O [n][c] fp32, raw-reshape-equivalent) ->
// pixel-major padded bf16 xp [B][4356][512]. Borders pre-zeroed by k_fill0.
// grid (64 pix-tiles, 8 ch-tiles, B)
template <bool ADD>
__global__ __launch_bounds__(256) void k_padT(const float* __restrict__ x,
        const float* __restrict__ Oc, const float* __restrict__ Zp,
        short* __restrict__ xp) {
    __shared__ float Ts[64][68];
    int t = threadIdx.x;
    int n0 = blockIdx.x * 64, c0 = blockIdx.y * 64, b = blockIdx.z;
    float iz = ADD ? (1.0f / Zp[b]) : 1.0f;
    const float* xb = x + ((size_t)b * CIN + c0) * HW;
#pragma unroll
    for (int j = 0; j < 4; j++) {
        int slot = j * 256 + t;
        int r = slot >> 4, col = (slot & 15) * 4;
        float4 v = *(const float4*)(xb + (size_t)r * HW + n0 + col);
        *(float4*)&Ts[r][col] = v;
    }
    __syncthreads();
    short* xpb = xp + (size_t)b * PROW * CIN;
    const float* ob = ADD ? (Oc + (size_t)b * HW * CIN) : nullptr;
#pragma unroll
    for (int j = 0; j < 2; j++) {
        int slot = j * 256 + t;
        int pix = slot >> 3, ch = (slot & 7) * 8;
        int rp = prow(n0 + pix);
        float v[8];
#pragma unroll
        for (int k = 0; k < 8; k++) v[k] = Ts[ch + k][pix];
        if (ADD) {
            const float* os = ob + (size_t)(n0 + pix) * CIN + c0 + ch;
#pragma unroll
            for (int k = 0; k < 8; k += 4) {
                float4 o4 = *(const float4*)(os + k);
                v[k]   += o4.x * iz; v[k+1] += o4.y * iz;
                v[k+2] += o4.z * iz; v[k+3] += o4.w * iz;
            }
        }
        unsigned pk[4];
#pragma unroll
        for (int k = 0; k < 4; k++)
            pk[k] = f2bf(v[2*k]) | (f2bf(v[2*k+1]) << 16);
        *(uint4*)(xpb + (size_t)rp * CIN + c0 + ch) = *(uint4*)pk;
    }
}

// ---------------------------------------------------------------------------
// 1x1 convs: xt/xc[n][p] = sum_i xp[n][i]*w[p][i] + bias.  M=p(64), N=n(64), K=512
// grid (64 n-tiles, 8: b*2+which)
__global__ __launch_bounds__(256) void k_qk(const short* __restrict__ xp,
        const short* __restrict__ wtop, const short* __restrict__ wcen,
        const float* __restrict__ btop, const float* __restrict__ bcen,
        short* __restrict__ xt, short* __restrict__ xc) {
    __shared__ __align__(16) short As[2048];   // w: 64 rows(p) x 32(i)
    __shared__ __align__(16) short Bs[2048];   // x: 64 rows(n) x 32(i)
    int t = threadIdx.x;
    int n0 = blockIdx.x * 64;
    int b = blockIdx.y >> 1, which = blockIdx.y & 1;
    const short* w    = which ? wcen : wtop;
    const float* bias = which ? bcen : btop;
    short* out        = (which ? xc : xt) + (size_t)b * HW * PABN;
    const short* xb   = xp + (size_t)b * PROW * CIN;

    int arow = t >> 2, ach = t & 3;
    int sch = ach ^ ((arow >> 1) & 3);
    int rp = prow(n0 + arow);
    int lane = t & 63, wid = t >> 6, l15 = lane & 15, q = lane >> 4;
    int wm = wid >> 1, wn = wid & 1;
    int cx = (q ^ ((l15 >> 1) & 3)) * 8;
    ffrag acc[2][2] = {};

    for (int i0 = 0; i0 < CIN; i0 += 32) {
        gload16(w  + (size_t)arow * CIN + i0 + sch * 8, As + t * 8);
        gload16(xb + (size_t)rp   * CIN + i0 + sch * 8, Bs + t * 8);
        __syncthreads();
        bfrag a[2], bb[2];
        a[0]  = *(const bfrag*)(As + (wm * 32 + l15) * 32 + cx);
        a[1]  = *(const bfrag*)(As + (wm * 32 + 16 + l15) * 32 + cx);
        bb[0] = *(const bfrag*)(Bs + (wn * 32 + l15) * 32 + cx);
        bb[1] = *(const bfrag*)(Bs + (wn * 32 + 16 + l15) * 32 + cx);
        acc[0][0] = MFMA(a[0], bb[0], acc[0][0]);
        acc[0][1] = MFMA(a[0], bb[1], acc[0][1]);
        acc[1][0] = MFMA(a[1], bb[0], acc[1][0]);
        acc[1][1] = MFMA(a[1], bb[1], acc[1][1]);
        __syncthreads();
    }
#pragma unroll
    for (int mi = 0; mi < 2; mi++) {
        int p = wm * 32 + mi * 16 + q * 4;
        float4 bv = *(const float4*)(bias + p);
#pragma unroll
        for (int ni = 0; ni < 2; ni++) {
            int nn = n0 + wn * 32 + ni * 16 + l15;
            ffrag v = acc[mi][ni];
            uint2 u;
            u.x = f2bf(v.x + bv.x) | (f2bf(v.y + bv.y) << 16);
            u.y = f2bf(v.z + bv.z) | (f2bf(v.w + bv.w) << 16);
            *(uint2*)(out + (size_t)nn * PABN + p) = u;
        }
    }
}

// ---------------------------------------------------------------------------
// conv3x3 v3 (kept — round-8 win): counted-vmcnt pipeline, vmcnt(8) with
// full-iteration slack, per-tap hoisted addressing. LDS 64KB dbuf.
// M=n(128), N=o(128). grid (32 n-tiles, 4 o-tiles, B)
template <bool FP32OUT>
__global__ __launch_bounds__(256) void k_conv(const short* __restrict__ xin,
        const short* __restrict__ wT, const float* __restrict__ bias,
        void* __restrict__ outv) {
    __shared__ __align__(16) short As[2][8192];   // pixels: 128 x 64
    __shared__ __align__(16) short Bs[2][8192];   // weights: 128(o) x 64
    int t = threadIdx.x;
    int n0 = blockIdx.x * 128, o0 = blockIdx.y * 128, b = blockIdx.z;
    const short* xb = xin + (size_t)b * PROW * CIN;
    int lane = t & 63, wid = t >> 6, l15 = lane & 15, q = lane >> 4;
    int wm = wid >> 1, wn = wid & 1;
    int arow = t >> 3, ach = t & 7;
    int sch = ach ^ (arow & 7);
    int pr[4];
#pragma unroll
    for (int j = 0; j < 4; j++) pr[j] = prow(n0 + j * 32 + arow);
    ffrag acc[4][4] = {};

    auto stage = [&](int k9s, int i0, int bsel) {
        int kh = k9s / 3, kw = k9s - kh * 3;       // hoisted per-tap by unroll
        int sh = (kh - 1) * 66 + (kw - 1);
        const short* wk = wT + (size_t)k9s * CIN * CIN;
#pragma unroll
        for (int j = 0; j < 4; j++) {
            gload16(xb + (size_t)(pr[j] + sh) * CIN + i0 + sch * 8,
                    &As[bsel][(j * 256 + t) * 8]);
            gload16(wk + (size_t)(o0 + j * 32 + arow) * CIN + i0 + sch * 8,
                    &Bs[bsel][(j * 256 + t) * 8]);
        }
    };

    stage(0, 0, 0);                                // pipeline prologue

    for (int k9 = 0; k9 < 9; ++k9) {
#pragma unroll
        for (int i8 = 0; i8 < 8; ++i8) {
            int ks = k9 * 8 + i8;
            int cur = i8 & 1;                      // == ks & 1
            if (ks < 71) {                         // issue next-step loads
                if (i8 < 7) stage(k9, (i8 + 1) * 64, cur ^ 1);
                else        stage(k9 + 1, 0, cur ^ 1);
                asm volatile("s_waitcnt vmcnt(8)" ::: "memory");  // stage(ks) in
            } else {
                asm volatile("s_waitcnt vmcnt(0)" ::: "memory");
            }
            __builtin_amdgcn_s_barrier();          // B1: tile ks visible to all
            asm volatile("" ::: "memory");
            __builtin_amdgcn_s_setprio(1);
#pragma unroll
            for (int kc = 0; kc < 2; kc++) {
                int cx = (((kc * 4 + q) ^ (l15 & 7))) * 8;
                bfrag a[4], bb[4];
#pragma unroll
                for (int mi = 0; mi < 4; mi++)
                    a[mi] = *(const bfrag*)(&As[cur][(wm * 64 + mi * 16 + l15) * 64 + cx]);
#pragma unroll
                for (int ni = 0; ni < 4; ni++)
                    bb[ni] = *(const bfrag*)(&Bs[cur][(wn * 64 + ni * 16 + l15) * 64 + cx]);
#pragma unroll
                for (int mi = 0; mi < 4; mi++)
#pragma unroll
                    for (int ni = 0; ni < 4; ni++)
                        acc[mi][ni] = MFMA(a[mi], bb[ni], acc[mi][ni]);
            }
            __builtin_amdgcn_s_setprio(0);
            asm volatile("" ::: "memory");
            __builtin_amdgcn_s_barrier();          // B2: reads of buf cur done
            asm volatile("" ::: "memory");
        }
    }
#pragma unroll
    for (int ni = 0; ni < 4; ni++) {
        int o = o0 + wn * 64 + ni * 16 + l15;
        float bv = bias[o];
#pragma unroll
        for (int mi = 0; mi < 4; mi++) {
            int n = n0 + wm * 64 + mi * 16 + q * 4;
            ffrag v = acc[mi][ni];
            if (FP32OUT) {
                float* out = (float*)outv + (size_t)b * CIN * HW;
                *(float4*)(out + (size_t)o * HW + n) =
                    make_float4(v.x + bv, v.y + bv, v.z + bv, v.w + bv);
            } else {
                short* out = (short*)outv + (size_t)b * CIN * HW;
                uint2 u;
                u.x = f2bf(v.x + bv) | (f2bf(v.y + bv) << 16);
                u.y = f2bf(v.z + bv) | (f2bf(v.w + bv) << 16);
                *(uint2*)(out + (size_t)o * HW + n) = u;
            }
        }
    }
}

// ---------------------------------------------------------------------------
// Fused S+PV v5 (RESTORED — round-9 best, 121.6us; v7's 4-block split
// regressed to 205us: occupancy never rose past 23% and 4x exp duplication
// made VALU the bottleneck at 45% busy):
//   c-FULL blocks, tile 64n x 512c, one batch. 8 waves (512 thr), 1 block/CU,
//   grid 256 XCD-swizzled. S phase wave=(nset=wid&3, mhalf=wid>>2) computes
//   16n x 32m (4 MFMA); exp 8 vals/thread computed ONCE. PV: wave owns
//   c-64 x n-64 (32 MFMA).
//   LDS 90KB: XT[2][64][64] dbuf | XB[512][64] SINGLE | PS[64][64] (XC staged
//   through PS in prologue). Per iter, 2 barriers:
//     A: issue XT(it+1); S 4-MFMA; exp->PS
//     B1: lgkmcnt(0) + vmcnt(1)  [XB(it) landed; XT(it+1) may fly]
//     PV 32 MFMA (XB + PS)
//     B2: vmcnt(0)               [XT(it+1) landed; XB reads done]
//     C: issue XB(it+1) x8       [lands under next A-phase, checked at next B1]
__global__ __launch_bounds__(512) void k_fused(const short* __restrict__ xc,
        const short* __restrict__ xt, const short* __restrict__ xb,
        float* __restrict__ O, float* __restrict__ Zbuf) {
    __shared__ __align__(16) short SM[45056];   // 90112 B
    __shared__ float red[8];
    short* XT0 = SM;                  // [2][64][64]
    short* XBs = SM + 8192;           // [512][64] single
    short* PS  = SM + 40960;          // [64][64]

    int wg = ((blockIdx.x & 7) << 5) | (blockIdx.x >> 3);   // XCD-contiguous
    int b = wg >> 6, ntile = wg & 63;
    int n0 = ntile * 64;
    const short* xcb = xc + (size_t)b * HW * PABN;
    const short* xtb = xt + (size_t)b * HW * PABN;
    const short* xbb = xb + (size_t)b * CIN * HW;

    int t = threadIdx.x;
    int lane = t & 63, wid = t >> 6, l15 = lane & 15, q = lane >> 4;
    int srow = t >> 3, sch = (t & 7) ^ (srow & 7);   // staging row / swizzled chunk
    int nset = wid & 3, mhalf = wid >> 2;            // S-phase wave role

    // ---- prologue: XC -> PS area, XT(0), XB(0)
    gload16(xcb + (size_t)(n0 + srow) * PABN + sch * 8, PS + t * 8);
    gload16(xtb + (size_t)srow * PABN + sch * 8, XT0 + t * 8);
#pragma unroll
    for (int j = 0; j < 8; j++)
        gload16(xbb + (size_t)(j * 64 + srow) * HW + sch * 8,
                XBs + (j * 512 + t) * 8);
    asm volatile("s_waitcnt vmcnt(0)" ::: "memory");
    __builtin_amdgcn_s_barrier();
    asm volatile("" ::: "memory");
    bfrag aS[2];                                // loop-invariant xc A-frags
#pragma unroll
    for (int kc = 0; kc < 2; kc++)
        aS[kc] = *(const bfrag*)(PS + (nset * 16 + l15) * 64
                                 + ((kc * 4 + q) ^ (l15 & 7)) * 8);
    asm volatile("s_waitcnt lgkmcnt(0)" ::: "memory");
    __builtin_amdgcn_s_barrier();               // PS now reusable
    asm volatile("" ::: "memory");

    ffrag acc[4][4] = {};
    float zacc = 0.f;
    int nrow = nset * 16 + q * 4;

    for (int it = 0; it < 64; ++it) {
        const short* XTc = XT0 + (it & 1) * 4096;
        // ---- A: issue XT(it+1); S(it) 4 MFMA; exp -> PS
        if (it < 63)
            gload16(xtb + (size_t)((it + 1) * 64 + srow) * PABN + sch * 8,
                    XT0 + ((it & 1) ^ 1) * 4096 + t * 8);
        ffrag s[2] = {};
        __builtin_amdgcn_s_setprio(1);
#pragma unroll
        for (int mi = 0; mi < 2; mi++)
#pragma unroll
            for (int kc = 0; kc < 2; kc++) {
                bfrag bf = *(const bfrag*)(XTc + (mhalf * 32 + mi * 16 + l15) * 64
                                           + ((kc * 4 + q) ^ (l15 & 7)) * 8);
                s[mi] = MFMA(aS[kc], bf, s[mi]);
            }
        __builtin_amdgcn_s_setprio(0);
#pragma unroll
        for (int mi = 0; mi < 2; mi++) {
            int cc = mhalf * 4 + mi * 2 + (l15 >> 3), jj = l15 & 7;
#pragma unroll
            for (int r = 0; r < 4; r++) {
                float e = __expf(s[mi][r]);
                zacc += e;
                PS[(nrow + r) * 64 + (cc ^ ((nrow + r) & 7)) * 8 + jj] =
                    (short)f2bf(e);
            }
        }
        if (it < 63) asm volatile("s_waitcnt vmcnt(1) lgkmcnt(0)" ::: "memory");
        else         asm volatile("s_waitcnt vmcnt(0) lgkmcnt(0)" ::: "memory");
        __builtin_amdgcn_s_barrier();           // B1: PS(it)+XB(it) visible
        asm volatile("" ::: "memory");
        // ---- PV: acc[c][n] += xb . P^T  (wave: c-64 x n-64)
        __builtin_amdgcn_s_setprio(1);
#pragma unroll
        for (int kc = 0; kc < 2; kc++) {
            int cx = ((kc * 4 + q) ^ (l15 & 7)) * 8;
            bfrag av[4], bv[4];
#pragma unroll
            for (int ci = 0; ci < 4; ci++)
                av[ci] = *(const bfrag*)(XBs + (wid * 64 + ci * 16 + l15) * 64 + cx);
#pragma unroll
            for (int nj = 0; nj < 4; nj++)
                bv[nj] = *(const bfrag*)(PS + (nj * 16 + l15) * 64 + cx);
#pragma unroll
            for (int ci = 0; ci < 4; ci++)
#pragma unroll
                for (int nj = 0; nj < 4; nj++)
                    acc[ci][nj] = MFMA(av[ci], bv[nj], acc[ci][nj]);
        }
        __builtin_amdgcn_s_setprio(0);
        if (it < 63) asm volatile("s_waitcnt vmcnt(0)" ::: "memory"); // XT(it+1) in
        __builtin_amdgcn_s_barrier();           // B2: XB/PS reads done
        asm volatile("" ::: "memory");
        // ---- C: issue XB(it+1) staging (lands under next A phase)
        if (it < 63) {
            int m1 = (it + 1) * 64;
#pragma unroll
            for (int j = 0; j < 8; j++)
                gload16(xbb + (size_t)(j * 64 + srow) * HW + m1 + sch * 8,
                        XBs + (j * 512 + t) * 8);
        }
    }

    // ---- z reduce (every value exp'd exactly once)
#pragma unroll
    for (int off = 32; off > 0; off >>= 1) zacc += __shfl_down(zacc, off, 64);
    if (lane == 0) red[wid] = zacc;
    __syncthreads();
    if (t == 0) {
        float z = 0.f;
#pragma unroll
        for (int i = 0; i < 8; i++) z += red[i];
        Zbuf[b * 64 + ntile] = z;
    }
    // ---- O store (unscaled fp32, [n][c]; invZ applied in k_padT<true>)
    float* Ob = O + (size_t)b * HW * CIN;
#pragma unroll
    for (int ci = 0; ci < 4; ci++)
#pragma unroll
        for (int nj = 0; nj < 4; nj++) {
            int n = n0 + nj * 16 + l15;
            int c = wid * 64 + ci * 16 + q * 4;
            ffrag v = acc[ci][nj];
            *(float4*)(Ob + (size_t)n * CIN + c) =
                make_float4(v.x, v.y, v.z, v.w);
        }
}

// ---------------------------------------------------------------------------
// Reduce Zbuf[b][0..63] -> Z[b]. 1 block, 256 thr (wave per batch).
__global__ __launch_bounds__(256) void k_redz(const float* __restrict__ Zbuf,
        float* __restrict__ Z) {
    int wid = threadIdx.x >> 6, lane = threadIdx.x & 63;
    float s = Zbuf[wid * 64 + lane];
#pragma unroll
    for (int off = 32; off > 0; off >>= 1) s += __shfl_down(s, off, 64);
    if (lane == 0) Z[wid] = s;
}

// ---------------------------------------------------------------------------
extern "C" void kernel_launch(void* const* d_in, const int* in_sizes, int n_in,
                              void* d_out, int out_size, void* d_ws, size_t ws_size,
                              hipStream_t stream) {
    const float* x     = (const float*)d_in[0];
    const float* w_top = (const float*)d_in[1];
    const float* b_top = (const float*)d_in[2];
    const float* w_cen = (const float*)d_in[3];
    const float* b_cen = (const float*)d_in[4];
    const float* w_bot = (const float*)d_in[5];
    const float* b_bot = (const float*)d_in[6];
    const float* w_out = (const float*)d_in[7];
    const float* b_out = (const float*)d_in[8];

    char* W = (char*)d_ws;
    short* xp   = (short*)(W);               // 17,842,176 B (also reused as yp)
    short* xt   = (short*)(W + 17842176);    //  2,097,152
    short* xc   = (short*)(W + 19939328);    //  2,097,152
    short* wtb  = (short*)(W + 22036480);    //     65,536
    short* wcb  = (short*)(W + 22102016);    //     65,536
    short* wbT  = (short*)(W + 22167552);    //  4,718,592
    short* woT  = (short*)(W + 26886144);    //  4,718,592
    short* xbc  = (short*)(W + 31604736);    // 16,777,216
    float* O    = (float*)(W + 48381952);    // 33,554,432 (unscaled PV output)
    float* Z    = (float*)(W + 81936384);    //        512
    float* Zbuf = (float*)(W + 81936896);    //     16,384 (uses 256 floats)

    k_fill0<<<4356, 256, 0, stream>>>((uint4*)xp);           // zero padded buffer
    k_wpc<<<dim3(32, 2), 256, 0, stream>>>(w_top, w_cen, wtb, wcb);
    k_w9<<<dim3(512, 2, 2), 256, 0, stream>>>(w_bot, w_out, wbT, woT);
    k_padT<false><<<dim3(64, 8, BATCH), 256, 0, stream>>>(x, nullptr, nullptr, xp);
    k_qk<<<dim3(64, 8), 256, 0, stream>>>(xp, wtb, wcb, b_top, b_cen, xt, xc);
    k_conv<false><<<dim3(32, 4, BATCH), 256, 0, stream>>>(xp, wbT, b_bot, xbc);
    k_fused<<<dim3(256), 512, 0, stream>>>(xc, xt, xbc, O, Zbuf);
    k_redz<<<1, 256, 0, stream>>>(Zbuf, Z);
    k_padT<true><<<dim3(64, 8, BATCH), 256, 0, stream>>>(x, O, Z, xp);  // y -> xp
    k_conv<true><<<dim3(32, 4, BATCH), 256, 0, stream>>>(xp, woT, b_out, (float*)d_out);
}

// Round 13
// 391.571 us; speedup vs baseline: 1.1700x; 1.0025x over previous
//
#include <hip/hip_runtime.h>
#include <math.h>

#define BATCH 4
#define CIN   512
#define PABN  64
#define HW    4096
#define PROW  4356            // 66*66 padded pixel rows

typedef __attribute__((ext_vector_type(8))) short bfrag;   // 8 bf16
typedef __attribute__((ext_vector_type(4))) float ffrag;   // 4 fp32
#define MFMA(a, b, c) __builtin_amdgcn_mfma_f32_16x16x32_bf16(a, b, c, 0, 0, 0)

__device__ __forceinline__ void gload16(const void* g, void* l) {
    __builtin_amdgcn_global_load_lds(
        (const __attribute__((address_space(1))) unsigned int*)g,
        (__attribute__((address_space(3))) unsigned int*)l, 16, 0, 0);
}

__device__ __forceinline__ unsigned f2bf(float f) {   // fp32 -> bf16 bits, RNE
    unsigned u = __float_as_uint(f);
    return (u + 0x7fffu + ((u >> 16) & 1u)) >> 16;
}

// padded row index for pixel n: (h+1)*66 + (w+1) = n + 2*(n>>6) + 67
__device__ __forceinline__ int prow(int n) { return n + 2 * (n >> 6) + 67; }

// ---------------------------------------------------------------------------
// Zero ONLY the 260 border rows per batch of the padded buffer (interior rows
// are fully overwritten by k_padT). 260 rows x 512 shorts = 16640 uint4/batch.
// rows: 0..65 (top), 4290..4355 (bottom), h*66 and h*66+65 for h=1..64.
// grid (65, BATCH) x 256 thr: thread tid writes uint4 #tid (64 per row).
__global__ __launch_bounds__(256) void k_fillb(short* __restrict__ xp) {
    int tid = blockIdx.x * 256 + threadIdx.x;      // 0..16639
    int rowidx = tid >> 6, c8 = (tid & 63) * 8;
    int r;
    if (rowidx < 66)       r = rowidx;
    else if (rowidx < 132) r = 4290 + (rowidx - 66);
    else {
        int i = rowidx - 132;                      // 0..127
        r = ((i >> 1) + 1) * 66 + ((i & 1) ? 65 : 0);
    }
    short* xpb = xp + (size_t)blockIdx.y * PROW * CIN;
    uint4 z; z.x = z.y = z.z = z.w = 0u;
    *(uint4*)(xpb + (size_t)r * CIN + c8) = z;
}

// w_top/w_cen [64][512] fp32 -> bf16 (layout kept: [p][i], K=i contiguous)
__global__ __launch_bounds__(256) void k_wpc(const float* __restrict__ wt,
        const float* __restrict__ wc, short* __restrict__ ot, short* __restrict__ oc) {
    const float* src = blockIdx.y ? wc : wt;
    short* dst       = blockIdx.y ? oc : ot;
    int idx = (blockIdx.x * 256 + threadIdx.x) * 4;
    float4 v = *(const float4*)(src + idx);
    uint2 u;
    u.x = f2bf(v.x) | (f2bf(v.y) << 16);
    u.y = f2bf(v.z) | (f2bf(v.w) << 16);
    *(uint2*)(dst + idx) = u;
}

// w [O][I][3][3] fp32 -> wT[k][o][i] bf16
__global__ __launch_bounds__(256) void k_w9(const float* __restrict__ wb,
        const float* __restrict__ wo, short* __restrict__ wbT, short* __restrict__ woT) {
    const float* w = blockIdx.z ? wo : wb;
    short* wT      = blockIdx.z ? woT : wbT;
    int o = blockIdx.x;
    int i = blockIdx.y * 256 + threadIdx.x;
    const float* src = w + ((size_t)o * CIN + i) * 9;
    float v[9];
#pragma unroll
    for (int k = 0; k < 9; k++) v[k] = src[k];
#pragma unroll
    for (int k = 0; k < 9; k++)
        wT[((size_t)k * CIN + o) * CIN + i] = (short)f2bf(v[k]);
}

// ---------------------------------------------------------------------------
// x [B][512][4096] fp32 (ADD: + invZ * O [n][c] fp32, raw-reshape-equivalent) ->
// pixel-major padded bf16 xp [B][4356][512]. Borders pre-zeroed by k_fillb.
// grid (64 pix-tiles, 8 ch-tiles, B)
template <bool ADD>
__global__ __launch_bounds__(256) void k_padT(const float* __restrict__ x,
        const float* __restrict__ Oc, const float* __restrict__ Zp,
        short* __restrict__ xp) {
    __shared__ float Ts[64][68];
    int t = threadIdx.x;
    int n0 = blockIdx.x * 64, c0 = blockIdx.y * 64, b = blockIdx.z;
    float iz = ADD ? (1.0f / Zp[b]) : 1.0f;
    const float* xb = x + ((size_t)b * CIN + c0) * HW;
#pragma unroll
    for (int j = 0; j < 4; j++) {
        int slot = j * 256 + t;
        int r = slot >> 4, col = (slot & 15) * 4;
        float4 v = *(const float4*)(xb + (size_t)r * HW + n0 + col);
        *(float4*)&Ts[r][col] = v;
    }
    __syncthreads();
    short* xpb = xp + (size_t)b * PROW * CIN;
    const float* ob = ADD ? (Oc + (size_t)b * HW * CIN) : nullptr;
#pragma unroll
    for (int j = 0; j < 2; j++) {
        int slot = j * 256 + t;
        int pix = slot >> 3, ch = (slot & 7) * 8;
        int rp = prow(n0 + pix);
        float v[8];
#pragma unroll
        for (int k = 0; k < 8; k++) v[k] = Ts[ch + k][pix];
        if (ADD) {
            const float* os = ob + (size_t)(n0 + pix) * CIN + c0 + ch;
#pragma unroll
            for (int k = 0; k < 8; k += 4) {
                float4 o4 = *(const float4*)(os + k);
                v[k]   += o4.x * iz; v[k+1] += o4.y * iz;
                v[k+2] += o4.z * iz; v[k+3] += o4.w * iz;
            }
        }
        unsigned pk[4];
#pragma unroll
        for (int k = 0; k < 4; k++)
            pk[k] = f2bf(v[2*k]) | (f2bf(v[2*k+1]) << 16);
        *(uint4*)(xpb + (size_t)rp * CIN + c0 + ch) = *(uint4*)pk;
    }
}

// ---------------------------------------------------------------------------
// 1x1 convs: xt/xc[n][p] = sum_i xp[n][i]*w[p][i] + bias.  M=p(64), N=n(64), K=512
// grid (64 n-tiles, 8: b*2+which)
__global__ __launch_bounds__(256) void k_qk(const short* __restrict__ xp,
        const short* __restrict__ wtop, const short* __restrict__ wcen,
        const float* __restrict__ btop, const float* __restrict__ bcen,
        short* __restrict__ xt, short* __restrict__ xc) {
    __shared__ __align__(16) short As[2048];   // w: 64 rows(p) x 32(i)
    __shared__ __align__(16) short Bs[2048];   // x: 64 rows(n) x 32(i)
    int t = threadIdx.x;
    int n0 = blockIdx.x * 64;
    int b = blockIdx.y >> 1, which = blockIdx.y & 1;
    const short* w    = which ? wcen : wtop;
    const float* bias = which ? bcen : btop;
    short* out        = (which ? xc : xt) + (size_t)b * HW * PABN;
    const short* xb   = xp + (size_t)b * PROW * CIN;

    int arow = t >> 2, ach = t & 3;
    int sch = ach ^ ((arow >> 1) & 3);
    int rp = prow(n0 + arow);
    int lane = t & 63, wid = t >> 6, l15 = lane & 15, q = lane >> 4;
    int wm = wid >> 1, wn = wid & 1;
    int cx = (q ^ ((l15 >> 1) & 3)) * 8;
    ffrag acc[2][2] = {};

    for (int i0 = 0; i0 < CIN; i0 += 32) {
        gload16(w  + (size_t)arow * CIN + i0 + sch * 8, As + t * 8);
        gload16(xb + (size_t)rp   * CIN + i0 + sch * 8, Bs + t * 8);
        __syncthreads();
        bfrag a[2], bb[2];
        a[0]  = *(const bfrag*)(As + (wm * 32 + l15) * 32 + cx);
        a[1]  = *(const bfrag*)(As + (wm * 32 + 16 + l15) * 32 + cx);
        bb[0] = *(const bfrag*)(Bs + (wn * 32 + l15) * 32 + cx);
        bb[1] = *(const bfrag*)(Bs + (wn * 32 + 16 + l15) * 32 + cx);
        acc[0][0] = MFMA(a[0], bb[0], acc[0][0]);
        acc[0][1] = MFMA(a[0], bb[1], acc[0][1]);
        acc[1][0] = MFMA(a[1], bb[0], acc[1][0]);
        acc[1][1] = MFMA(a[1], bb[1], acc[1][1]);
        __syncthreads();
    }
#pragma unroll
    for (int mi = 0; mi < 2; mi++) {
        int p = wm * 32 + mi * 16 + q * 4;
        float4 bv = *(const float4*)(bias + p);
#pragma unroll
        for (int ni = 0; ni < 2; ni++) {
            int nn = n0 + wn * 32 + ni * 16 + l15;
            ffrag v = acc[mi][ni];
            uint2 u;
            u.x = f2bf(v.x + bv.x) | (f2bf(v.y + bv.y) << 16);
            u.y = f2bf(v.z + bv.z) | (f2bf(v.w + bv.w) << 16);
            *(uint2*)(out + (size_t)nn * PABN + p) = u;
        }
    }
}

// ---------------------------------------------------------------------------
// conv3x3 v4 = v3 (counted-vmcnt pipeline) + XCD-aware block swizzle.
//   grid 512 (1D): g = (bid&7)*64 + bid>>3; decode o fastest, then n, then b:
//   o = g&3, nt = (g>>2)&31, b = g>>7.  Each XCD owns 16 contiguous n-tiles x
//   all 4 o-tiles x 1 batch -> per-XCD A working set ~4.3MB ~= L2; co-resident
//   CU blocks (adjacent g) share the same A-panel with different o (B differs).
// M=n(128), N=o(128). LDS 64KB dbuf, 2 blocks/CU.
// (resubmit — round-12 was a container-infra failure; source unchanged)
template <bool FP32OUT>
__global__ __launch_bounds__(256) void k_conv(const short* __restrict__ xin,
        const short* __restrict__ wT, const float* __restrict__ bias,
        void* __restrict__ outv) {
    __shared__ __align__(16) short As[2][8192];   // pixels: 128 x 64
    __shared__ __align__(16) short Bs[2][8192];   // weights: 128(o) x 64
    int t = threadIdx.x;
    int g = ((blockIdx.x & 7) << 6) | (blockIdx.x >> 3);   // XCD-chunked (512%8==0)
    int o0 = (g & 3) * 128, n0 = ((g >> 2) & 31) * 128, b = g >> 7;
    const short* xb = xin + (size_t)b * PROW * CIN;
    int lane = t & 63, wid = t >> 6, l15 = lane & 15, q = lane >> 4;
    int wm = wid >> 1, wn = wid & 1;
    int arow = t >> 3, ach = t & 7;
    int sch = ach ^ (arow & 7);
    int pr[4];
#pragma unroll
    for (int j = 0; j < 4; j++) pr[j] = prow(n0 + j * 32 + arow);
    ffrag acc[4][4] = {};

    auto stage = [&](int k9s, int i0, int bsel) {
        int kh = k9s / 3, kw = k9s - kh * 3;       // hoisted per-tap by unroll
        int sh = (kh - 1) * 66 + (kw - 1);
        const short* wk = wT + (size_t)k9s * CIN * CIN;
#pragma unroll
        for (int j = 0; j < 4; j++) {
            gload16(xb + (size_t)(pr[j] + sh) * CIN + i0 + sch * 8,
                    &As[bsel][(j * 256 + t) * 8]);
            gload16(wk + (size_t)(o0 + j * 32 + arow) * CIN + i0 + sch * 8,
                    &Bs[bsel][(j * 256 + t) * 8]);
        }
    };

    stage(0, 0, 0);                                // pipeline prologue

    for (int k9 = 0; k9 < 9; ++k9) {
#pragma unroll
        for (int i8 = 0; i8 < 8; ++i8) {
            int ks = k9 * 8 + i8;
            int cur = i8 & 1;                      // == ks & 1
            if (ks < 71) {                         // issue next-step loads
                if (i8 < 7) stage(k9, (i8 + 1) * 64, cur ^ 1);
                else        stage(k9 + 1, 0, cur ^ 1);
                asm volatile("s_waitcnt vmcnt(8)" ::: "memory");  // stage(ks) in
            } else {
                asm volatile("s_waitcnt vmcnt(0)" ::: "memory");
            }
            __builtin_amdgcn_s_barrier();          // B1: tile ks visible to all
            asm volatile("" ::: "memory");
            __builtin_amdgcn_s_setprio(1);
#pragma unroll
            for (int kc = 0; kc < 2; kc++) {
                int cx = (((kc * 4 + q) ^ (l15 & 7))) * 8;
                bfrag a[4], bb[4];
#pragma unroll
                for (int mi = 0; mi < 4; mi++)
                    a[mi] = *(const bfrag*)(&As[cur][(wm * 64 + mi * 16 + l15) * 64 + cx]);
#pragma unroll
                for (int ni = 0; ni < 4; ni++)
                    bb[ni] = *(const bfrag*)(&Bs[cur][(wn * 64 + ni * 16 + l15) * 64 + cx]);
#pragma unroll
                for (int mi = 0; mi < 4; mi++)
#pragma unroll
                    for (int ni = 0; ni < 4; ni++)
                        acc[mi][ni] = MFMA(a[mi], bb[ni], acc[mi][ni]);
            }
            __builtin_amdgcn_s_setprio(0);
            asm volatile("" ::: "memory");
            __builtin_amdgcn_s_barrier();          // B2: reads of buf cur done
            asm volatile("" ::: "memory");
        }
    }
#pragma unroll
    for (int ni = 0; ni < 4; ni++) {
        int o = o0 + wn * 64 + ni * 16 + l15;
        float bv = bias[o];
#pragma unroll
        for (int mi = 0; mi < 4; mi++) {
            int n = n0 + wm * 64 + mi * 16 + q * 4;
            ffrag v = acc[mi][ni];
            if (FP32OUT) {
                float* out = (float*)outv + (size_t)b * CIN * HW;
                *(float4*)(out + (size_t)o * HW + n) =
                    make_float4(v.x + bv, v.y + bv, v.z + bv, v.w + bv);
            } else {
                short* out = (short*)outv + (size_t)b * CIN * HW;
                uint2 u;
                u.x = f2bf(v.x + bv) | (f2bf(v.y + bv) << 16);
                u.y = f2bf(v.z + bv) | (f2bf(v.w + bv) << 16);
                *(uint2*)(out + (size_t)o * HW + n) = u;
            }
        }
    }
}

// ---------------------------------------------------------------------------
// Fused S+PV v5 (round-9 best, ~122us):
//   c-FULL blocks, tile 64n x 512c, one batch. 8 waves (512 thr), 1 block/CU,
//   grid 256 XCD-swizzled. S phase wave=(nset=wid&3, mhalf=wid>>2) computes
//   16n x 32m (4 MFMA); exp 8 vals/thread computed ONCE. PV: wave owns
//   c-64 x n-64 (32 MFMA).
//   LDS 90KB: XT[2][64][64] dbuf | XB[512][64] SINGLE | PS[64][64] (XC staged
//   through PS in prologue). Per iter, 2 barriers:
//     A: issue XT(it+1); S 4-MFMA; exp->PS
//     B1: lgkmcnt(0) + vmcnt(1)  [XB(it) landed; XT(it+1) may fly]
//     PV 32 MFMA (XB + PS)
//     B2: vmcnt(0)               [XT(it+1) landed; XB reads done]
//     C: issue XB(it+1) x8       [lands under next A-phase, checked at next B1]
__global__ __launch_bounds__(512) void k_fused(const short* __restrict__ xc,
        const short* __restrict__ xt, const short* __restrict__ xb,
        float* __restrict__ O, float* __restrict__ Zbuf) {
    __shared__ __align__(16) short SM[45056];   // 90112 B
    __shared__ float red[8];
    short* XT0 = SM;                  // [2][64][64]
    short* XBs = SM + 8192;           // [512][64] single
    short* PS  = SM + 40960;          // [64][64]

    int wg = ((blockIdx.x & 7) << 5) | (blockIdx.x >> 3);   // XCD-contiguous
    int b = wg >> 6, ntile = wg & 63;
    int n0 = ntile * 64;
    const short* xcb = xc + (size_t)b * HW * PABN;
    const short* xtb = xt + (size_t)b * HW * PABN;
    const short* xbb = xb + (size_t)b * CIN * HW;

    int t = threadIdx.x;
    int lane = t & 63, wid = t >> 6, l15 = lane & 15, q = lane >> 4;
    int srow = t >> 3, sch = (t & 7) ^ (srow & 7);   // staging row / swizzled chunk
    int nset = wid & 3, mhalf = wid >> 2;            // S-phase wave role

    // ---- prologue: XC -> PS area, XT(0), XB(0)
    gload16(xcb + (size_t)(n0 + srow) * PABN + sch * 8, PS + t * 8);
    gload16(xtb + (size_t)srow * PABN + sch * 8, XT0 + t * 8);
#pragma unroll
    for (int j = 0; j < 8; j++)
        gload16(xbb + (size_t)(j * 64 + srow) * HW + sch * 8,
                XBs + (j * 512 + t) * 8);
    asm volatile("s_waitcnt vmcnt(0)" ::: "memory");
    __builtin_amdgcn_s_barrier();
    asm volatile("" ::: "memory");
    bfrag aS[2];                                // loop-invariant xc A-frags
#pragma unroll
    for (int kc = 0; kc < 2; kc++)
        aS[kc] = *(const bfrag*)(PS + (nset * 16 + l15) * 64
                                 + ((kc * 4 + q) ^ (l15 & 7)) * 8);
    asm volatile("s_waitcnt lgkmcnt(0)" ::: "memory");
    __builtin_amdgcn_s_barrier();               // PS now reusable
    asm volatile("" ::: "memory");

    ffrag acc[4][4] = {};
    float zacc = 0.f;
    int nrow = nset * 16 + q * 4;

    for (int it = 0; it < 64; ++it) {
        const short* XTc = XT0 + (it & 1) * 4096;
        // ---- A: issue XT(it+1); S(it) 4 MFMA; exp -> PS
        if (it < 63)
            gload16(xtb + (size_t)((it + 1) * 64 + srow) * PABN + sch * 8,
                    XT0 + ((it & 1) ^ 1) * 4096 + t * 8);
        ffrag s[2] = {};
        __builtin_amdgcn_s_setprio(1);
#pragma unroll
        for (int mi = 0; mi < 2; mi++)
#pragma unroll
            for (int kc = 0; kc < 2; kc++) {
                bfrag bf = *(const bfrag*)(XTc + (mhalf * 32 + mi * 16 + l15) * 64
                                           + ((kc * 4 + q) ^ (l15 & 7)) * 8);
                s[mi] = MFMA(aS[kc], bf, s[mi]);
            }
        __builtin_amdgcn_s_setprio(0);
#pragma unroll
        for (int mi = 0; mi < 2; mi++) {
            int cc = mhalf * 4 + mi * 2 + (l15 >> 3), jj = l15 & 7;
#pragma unroll
            for (int r = 0; r < 4; r++) {
                float e = __expf(s[mi][r]);
                zacc += e;
                PS[(nrow + r) * 64 + (cc ^ ((nrow + r) & 7)) * 8 + jj] =
                    (short)f2bf(e);
            }
        }
        if (it < 63) asm volatile("s_waitcnt vmcnt(1) lgkmcnt(0)" ::: "memory");
        else         asm volatile("s_waitcnt vmcnt(0) lgkmcnt(0)" ::: "memory");
        __builtin_amdgcn_s_barrier();           // B1: PS(it)+XB(it) visible
        asm volatile("" ::: "memory");
        // ---- PV: acc[c][n] += xb . P^T  (wave: c-64 x n-64)
        __builtin_amdgcn_s_setprio(1);
#pragma unroll
        for (int kc = 0; kc < 2; kc++) {
            int cx = ((kc * 4 + q) ^ (l15 & 7)) * 8;
            bfrag av[4], bv[4];
#pragma unroll
            for (int ci = 0; ci < 4; ci++)
                av[ci] = *(const bfrag*)(XBs + (wid * 64 + ci * 16 + l15) * 64 + cx);
#pragma unroll
            for (int nj = 0; nj < 4; nj++)
                bv[nj] = *(const bfrag*)(PS + (nj * 16 + l15) * 64 + cx);
#pragma unroll
            for (int ci = 0; ci < 4; ci++)
#pragma unroll
                for (int nj = 0; nj < 4; nj++)
                    acc[ci][nj] = MFMA(av[ci], bv[nj], acc[ci][nj]);
        }
        __builtin_amdgcn_s_setprio(0);
        if (it < 63) asm volatile("s_waitcnt vmcnt(0)" ::: "memory"); // XT(it+1) in
        __builtin_amdgcn_s_barrier();           // B2: XB/PS reads done
        asm volatile("" ::: "memory");
        // ---- C: issue XB(it+1) staging (lands under next A phase)
        if (it < 63) {
            int m1 = (it + 1) * 64;
#pragma unroll
            for (int j = 0; j < 8; j++)
                gload16(xbb + (size_t)(j * 64 + srow) * HW + m1 + sch * 8,
                        XBs + (j * 512 + t) * 8);
        }
    }

    // ---- z reduce (every value exp'd exactly once)
#pragma unroll
    for (int off = 32; off > 0; off >>= 1) zacc += __shfl_down(zacc, off, 64);
    if (lane == 0) red[wid] = zacc;
    __syncthreads();
    if (t == 0) {
        float z = 0.f;
#pragma unroll
        for (int i = 0; i < 8; i++) z += red[i];
        Zbuf[b * 64 + ntile] = z;
    }
    // ---- O store (unscaled fp32, [n][c]; invZ applied in k_padT<true>)
    float* Ob = O + (size_t)b * HW * CIN;
#pragma unroll
    for (int ci = 0; ci < 4; ci++)
#pragma unroll
        for (int nj = 0; nj < 4; nj++) {
            int n = n0 + nj * 16 + l15;
            int c = wid * 64 + ci * 16 + q * 4;
            ffrag v = acc[ci][nj];
            *(float4*)(Ob + (size_t)n * CIN + c) =
                make_float4(v.x, v.y, v.z, v.w);
        }
}

// ---------------------------------------------------------------------------
// Reduce Zbuf[b][0..63] -> Z[b]. 1 block, 256 thr (wave per batch).
__global__ __launch_bounds__(256) void k_redz(const float* __restrict__ Zbuf,
        float* __restrict__ Z) {
    int wid = threadIdx.x >> 6, lane = threadIdx.x & 63;
    float s = Zbuf[wid * 64 + lane];
#pragma unroll
    for (int off = 32; off > 0; off >>= 1) s += __shfl_down(s, off, 64);
    if (lane == 0) Z[wid] = s;
}

// ---------------------------------------------------------------------------
extern "C" void kernel_launch(void* const* d_in, const int* in_sizes, int n_in,
                              void* d_out, int out_size, void* d_ws, size_t ws_size,
                              hipStream_t stream) {
    const float* x     = (const float*)d_in[0];
    const float* w_top = (const float*)d_in[1];
    const float* b_top = (const float*)d_in[2];
    const float* w_cen = (const float*)d_in[3];
    const float* b_cen = (const float*)d_in[4];
    const float* w_bot = (const float*)d_in[5];
    const float* b_bot = (const float*)d_in[6];
    const float* w_out = (const float*)d_in[7];
    const float* b_out = (const float*)d_in[8];

    char* W = (char*)d_ws;
    short* xp   = (short*)(W);               // 17,842,176 B (also reused as yp)
    short* xt   = (short*)(W + 17842176);    //  2,097,152
    short* xc   = (short*)(W + 19939328);    //  2,097,152
    short* wtb  = (short*)(W + 22036480);    //     65,536
    short* wcb  = (short*)(W + 22102016);    //     65,536
    short* wbT  = (short*)(W + 22167552);    //  4,718,592
    short* woT  = (short*)(W + 26886144);    //  4,718,592
    short* xbc  = (short*)(W + 31604736);    // 16,777,216
    float* O    = (float*)(W + 48381952);    // 33,554,432 (unscaled PV output)
    float* Z    = (float*)(W + 81936384);    //        512
    float* Zbuf = (float*)(W + 81936896);    //     16,384 (uses 256 floats)

    k_fillb<<<dim3(65, BATCH), 256, 0, stream>>>(xp);        // zero border rows only
    k_wpc<<<dim3(32, 2), 256, 0, stream>>>(w_top, w_cen, wtb, wcb);
    k_w9<<<dim3(512, 2, 2), 256, 0, stream>>>(w_bot, w_out, wbT, woT);
    k_padT<false><<<dim3(64, 8, BATCH), 256, 0, stream>>>(x, nullptr, nullptr, xp);
    k_qk<<<dim3(64, 8), 256, 0, stream>>>(xp, wtb, wcb, b_top, b_cen, xt, xc);
    k_conv<false><<<dim3(512), 256, 0, stream>>>(xp, wbT, b_bot, xbc);
    k_fused<<<dim3(256), 512, 0, stream>>>(xc, xt, xbc, O, Zbuf);
    k_redz<<<1, 256, 0, stream>>>(Zbuf, Z);
    k_padT<true><<<dim3(64, 8, BATCH), 256, 0, stream>>>(x, O, Z, xp);  // y -> xp
    k_conv<true><<<dim3(512), 256, 0, stream>>>(xp, woT, b_out, (float*)d_out);
}